// Round 13
// baseline (158.315 us; speedup 1.0000x reference)
//
#include <hip/hip_runtime.h>
#include <math.h>

// CliffordDDIDecoder — R13. R12 post-mortem: occupancy never rose because the
// GRID only supplies 2 blocks/CU (512 blocks); the LDS ceiling was moot. R13
// retargets R12's proven machinery to 32-row blocks / 1024-block grid =
// 4 blocks/CU (LDS ~26 KB, ceiling 6): quarter fragment-major h staging
// (8 KB), register prefetch of next quarter, W register-dbuf, 4 waves x
// (2 mt x 4 nt). Per-row numerics bit-identical to R12 (same chunk order,
// lane maps, 4-wave LN reduce). cliff/prep R7-verbatim. MFMA readout BANNED.

#define B_ 16384
#define D_ 512
#define H_ 256
#define R_ 95

typedef __attribute__((ext_vector_type(8))) short short8;   // 8 bf16
typedef __attribute__((ext_vector_type(4))) float f32x4;

#define MFMA(a, b, c) __builtin_amdgcn_mfma_f32_16x16x32_bf16(a, b, c, 0, 0, 0)

__device__ __forceinline__ short f2bf(float x) {            // fp32 -> bf16 RNE
    union { float f; unsigned u; } v; v.f = x;
    unsigned r = v.u + 0x7fffu + ((v.u >> 16) & 1u);
    return (short)(r >> 16);
}
__device__ __forceinline__ float bf2f(short s) {
    union { float f; unsigned u; } v;
    v.u = ((unsigned)(unsigned short)s) << 16;
    return v.f;
}

// exact GELU, erf via Abramowitz-Stegun 7.1.26 (max abs err 1.5e-7)
__device__ __forceinline__ float gelu_fast(float x) {
    const float z  = x * 0.70710678118654752f;
    const float az = fabsf(z);
    const float t  = 1.0f / fmaf(0.3275911f, az, 1.0f);
    float p = fmaf(1.061405429f, t, -1.453152027f);
    p = fmaf(p, t, 1.421413741f);
    p = fmaf(p, t, -0.284496736f);
    p = fmaf(p, t, 0.254829592f);
    p *= t;
    const float e  = 1.0f - p * __expf(-az * az);
    const float er = copysignf(e, z);
    return 0.5f * x * (1.0f + er);
}

// ---- prep: W1 -> [16 chunk][256 n][32 k] bf16 ; W2 -> [64 n][256 k] bf16 ----
__global__ __launch_bounds__(256)
void cdd_prep_kernel(const float* __restrict__ Wp1, const float* __restrict__ Wv1,
                     const float* __restrict__ Wp2, const float* __restrict__ Wv2,
                     short* __restrict__ W1c_p, short* __restrict__ W1c_v,
                     short* __restrict__ W2t_p, short* __restrict__ W2t_v)
{
    const int o = blockIdx.x * 256 + threadIdx.x;
    if (o < 16 * 256 * 32) {            // n-fast: coalesced W1 reads
        const int n = o & 255, kin = (o >> 8) & 31, ch = o >> 13;
        const int src = (ch * 32 + kin) * 256 + n;
        const int dst = ch * 8192 + n * 32 + kin;
        W1c_p[dst] = f2bf(Wp1[src]);
        W1c_v[dst] = f2bf(Wv1[src]);
    }
    if (o < 64 * 256) {
        const int n = o >> 8, k = o & 255;
        W2t_p[o] = f2bf(Wp2[k * 64 + n]);
        W2t_v[o] = f2bf(Wv2[k * 64 + n]);
    }
}

// ---- proj: x1=h@W1+b1 -> LN -> exact GELU -> m=x@W2+b2 (bf16 to ws) --------
// 32-row blocks, 256 thr (4 waves); wave w owns cols [64w,64w+64), mt 0..1.
// grid (512, 2) = 1024 blocks = 4 blocks/CU. LDS ~26 KB.
__global__ __launch_bounds__(256, 2)
void cdd_proj_kernel(const float* __restrict__ h_p, const float* __restrict__ h_v,
                     const float* __restrict__ bp1, const float* __restrict__ lgp,
                     const float* __restrict__ lbp, const float* __restrict__ bp2,
                     const float* __restrict__ bv1, const float* __restrict__ lgv,
                     const float* __restrict__ lbv, const float* __restrict__ bv2,
                     const short* __restrict__ W1c_p, const short* __restrict__ W1c_v,
                     const short* __restrict__ W2t_p, const short* __restrict__ W2t_v,
                     short* __restrict__ mp_out, short* __restrict__ mv_out)
{
    // hs: fragment-major quarter-strip (32 rows x 128 k), block bi = chl*2+mt:
    // 64 lanes x 8 bf16 contiguous -> ds_read_b128 lane-consecutive.
    __shared__ __align__(16) short hs[8 * 512];     // 8 KB
    __shared__ __align__(16) short xs[32 * 264];    // 16.9 KB
    __shared__ __align__(16) float lnbuf[256];      // 4 waves x 32 rows x 2

    const int which = blockIdx.y;
    const float* __restrict__ h   = which ? h_v : h_p;
    const float* __restrict__ b1  = which ? bv1 : bp1;
    const float* __restrict__ lg  = which ? lgv : lgp;
    const float* __restrict__ lb  = which ? lbv : lbp;
    const float* __restrict__ b2  = which ? bv2 : bp2;
    const short* __restrict__ W1c = which ? W1c_v : W1c_p;
    const short* __restrict__ W2t = which ? W2t_v : W2t_p;
    short* __restrict__ mo = which ? mv_out : mp_out;

    const int t = threadIdx.x;
    const int w = t >> 6, l = t & 63, q = l >> 4, c = l & 15;
    const int b0 = blockIdx.x * 32;
    // staging map: 8 threads/row; each thread covers 16 consecutive k of the
    // quarter (2 short8 writes). Per instr a wave covers 8 rows x 128 B.
    const int srow = t >> 3, kq8 = (t & 7) * 16;
    const int mt_s = srow >> 4, c_s = srow & 15;

    f32x4 acc1[2][4];
#pragma unroll
    for (int mt = 0; mt < 2; ++mt)
#pragma unroll
        for (int nt = 0; nt < 4; ++nt) acc1[mt][nt] = 0;

    const short* Wb0 = W1c + (w * 64 + c) * 32 + q * 8;
    short8 wb0[4], wb1[4];
#pragma unroll
    for (int nt = 0; nt < 4; ++nt) wb0[nt] = *(const short8*)(Wb0 + nt * 512);

    // prefetch quarter-0 h into registers (2 s-steps x 8 floats)
    const float* hbase = h + (size_t)(b0 + srow) * D_ + kq8;
    float4 ha[2], hb[2];
#pragma unroll
    for (int s = 0; s < 2; ++s) {
        ha[s] = *(const float4*)(hbase + s * 8);
        hb[s] = *(const float4*)(hbase + s * 8 + 4);
    }

    for (int qh = 0; qh < 4; ++qh) {
        // ---- stage this 128-k quarter (fragment-major bf16) from regs ----
        if (qh) __syncthreads();        // previous quarter's hs readers done
#pragma unroll
        for (int s = 0; s < 2; ++s) {
            short8 pk;
            pk[0] = f2bf(ha[s].x); pk[1] = f2bf(ha[s].y);
            pk[2] = f2bf(ha[s].z); pk[3] = f2bf(ha[s].w);
            pk[4] = f2bf(hb[s].x); pk[5] = f2bf(hb[s].y);
            pk[6] = f2bf(hb[s].z); pk[7] = f2bf(hb[s].w);
            // local k = kq8 + s*8 -> chunk chl = k>>5, quad qd = (k>>3)&3
            const int kk = kq8 + s * 8;
            const int chl = kk >> 5, qd = (kk >> 3) & 3;
            *(short8*)(hs + (chl * 2 + mt_s) * 512 + (qd * 16 + c_s) * 8) = pk;
        }
        if (qh < 3) {                   // issue next quarter's loads NOW
#pragma unroll
            for (int s = 0; s < 2; ++s) {
                ha[s] = *(const float4*)(hbase + (qh + 1) * 128 + s * 8);
                hb[s] = *(const float4*)(hbase + (qh + 1) * 128 + s * 8 + 4);
            }
        }
        __syncthreads();                // hs fully staged

        // ---- compute 4 chunks of this quarter; W register-dbuffered ----
        for (int chl = 0; chl < 4; ++chl) {
            const int g = qh * 4 + chl;                 // global chunk 0..15
            if (g < 15) {                               // prefetch next W batch
#pragma unroll
                for (int nt = 0; nt < 4; ++nt)
                    wb1[nt] = *(const short8*)(Wb0 + (g + 1) * 8192 + nt * 512);
            }
            const short8 a0 = *(const short8*)(hs + (chl * 2 + 0) * 512 + l * 8);
            const short8 a1 = *(const short8*)(hs + (chl * 2 + 1) * 512 + l * 8);
#pragma unroll
            for (int nt = 0; nt < 4; ++nt) {
                acc1[0][nt] = MFMA(a0, wb0[nt], acc1[0][nt]);
                acc1[1][nt] = MFMA(a1, wb0[nt], acc1[1][nt]);
            }
#pragma unroll
            for (int nt = 0; nt < 4; ++nt) wb0[nt] = wb1[nt];
        }
    }

    // ---------------- bias + LayerNorm (fp32 stats) + fast exact GELU ------
    float bb[4], gg[4], ee[4];
#pragma unroll
    for (int nt = 0; nt < 4; ++nt) {
        const int col = w * 64 + nt * 16 + c;
        bb[nt] = b1[col]; gg[nt] = lg[col]; ee[nt] = lb[col];
    }
#pragma unroll
    for (int mt = 0; mt < 2; ++mt)
#pragma unroll
        for (int reg = 0; reg < 4; ++reg) {
            float s1 = 0.f, s2 = 0.f;
#pragma unroll
            for (int nt = 0; nt < 4; ++nt) {
                const float a = acc1[mt][nt][reg] + bb[nt];
                acc1[mt][nt][reg] = a;
                s1 += a; s2 += a * a;
            }
#pragma unroll
            for (int m = 1; m <= 8; m <<= 1) {   // reduce over c (16 lanes)
                s1 += __shfl_xor(s1, m, 64);
                s2 += __shfl_xor(s2, m, 64);
            }
            if (c == 0) {
                const int row = mt * 16 + q * 4 + reg;
                *(float2*)(lnbuf + (w * 32 + row) * 2) = make_float2(s1, s2);
            }
        }
    __syncthreads();
#pragma unroll
    for (int mt = 0; mt < 2; ++mt)
#pragma unroll
        for (int reg = 0; reg < 4; ++reg) {
            const int row = mt * 16 + q * 4 + reg;
            float S1 = 0.f, S2 = 0.f;
#pragma unroll
            for (int w2 = 0; w2 < 4; ++w2) {
                const float2 p = *(const float2*)(lnbuf + (w2 * 32 + row) * 2);
                S1 += p.x; S2 += p.y;
            }
            const float mu  = S1 * (1.f / 256.f);
            const float var = S2 * (1.f / 256.f) - mu * mu;
            const float rs  = rsqrtf(var + 1e-5f);
#pragma unroll
            for (int nt = 0; nt < 4; ++nt) {
                const int col = w * 64 + nt * 16 + c;
                const float xv = (acc1[mt][nt][reg] - mu) * rs * gg[nt] + ee[nt];
                xs[row * 264 + col] = f2bf(gelu_fast(xv));
            }
        }
    __syncthreads();

    // ---------------- GEMM2: m(32x64) = xs(32x256) @ W2(256x64) + b2 -------
    // wave w owns n-cols [16w,16w+16); mt 0..1 (R7-proven pattern).
    f32x4 acc2[2]; acc2[0] = 0; acc2[1] = 0;
    const short* W2b = W2t + (w * 16 + c) * 256 + q * 8;
#pragma unroll
    for (int ks = 0; ks < 8; ++ks) {
        const short8 xa0 = *(const short8*)(xs + c * 264 + ks * 32 + q * 8);
        const short8 xa1 = *(const short8*)(xs + (16 + c) * 264 + ks * 32 + q * 8);
        const short8 wbk = *(const short8*)(W2b + ks * 32);
        acc2[0] = MFMA(xa0, wbk, acc2[0]);
        acc2[1] = MFMA(xa1, wbk, acc2[1]);
    }
    const float bc = b2[w * 16 + c];
#pragma unroll
    for (int mt = 0; mt < 2; ++mt)
#pragma unroll
        for (int reg = 0; reg < 4; ++reg) {
            const int row = mt * 16 + q * 4 + reg;
            mo[(size_t)(b0 + row) * 64 + w * 16 + c] = f2bf(acc2[mt][reg] + bc);
        }
}

// ---- cliff: R7-verbatim — Clifford collapse + VALU-dot readout, T in LDS ---
__global__ __launch_bounds__(256, 2)
void cdd_cliff_kernel(const short* __restrict__ mp, const short* __restrict__ mv,
                      const float* __restrict__ T, const float* __restrict__ gw,
                      float* __restrict__ out)
{
    __shared__ __align__(16) float wfl[32 * 68];    // collapsed w, fp32
    __shared__ __align__(16) float ts[95 * 68];     // T staged (pad 68)
    const int t  = threadIdx.x;
    const int b0 = blockIdx.x * 32;

    // stage T: 95 rows x 16 float4
#pragma unroll
    for (int k = 0; k < 6; ++k) {
        const int o = t + k * 256;
        if (o < 95 * 16) {
            const int rr = o >> 4, c4 = (o & 15) << 2;
            *(float4*)(ts + rr * 68 + c4) = *(const float4*)(T + rr * 64 + c4);
        }
    }

    // collapse: w[row][kq*8 .. +8] from mp,mv (fp32 math, bf16 inputs)
    {
        const int row = t >> 3, kq = t & 7;
        float g[8];
#pragma unroll
        for (int i = 0; i < 8; ++i) g[i] = gw[i];
        const short8 p8 = *(const short8*)(mp + (size_t)(b0 + row) * 64 + kq * 8);
        const short8 q8 = *(const short8*)(mv + (size_t)(b0 + row) * 64 + kq * 8);
        float mpv[8], mvv[8];
#pragma unroll
        for (int i = 0; i < 8; ++i) { mpv[i] = bf2f(p8[i]); mvv[i] = bf2f(q8[i]); }

        constexpr int MSK[8] = {0, 1, 2, 4, 3, 5, 6, 7};
        float v[8];
#pragma unroll
        for (int m = 0; m < 8; ++m) {
            float s = 0.f;
#pragma unroll
            for (int j = 0; j < 8; ++j) {
                const int am = MSK[m], bm = MSK[j];
                const int par = (__popc((am >> 1) & bm) + __popc((am >> 2) & bm)) & 1;
                const float sg = par ? -1.f : 1.f;
                s = fmaf(sg * g[MSK[am ^ bm]], mvv[j], s);
            }
            v[m] = s;
        }
#pragma unroll
        for (int l2 = 0; l2 < 8; ++l2) {
            float s = 0.f;
#pragma unroll
            for (int i = 0; i < 8; ++i) {
                const int am = MSK[i], bm = MSK[l2];
                const int par = (__popc((am >> 1) & bm) + __popc((am >> 2) & bm)) & 1;
                const float sg = par ? -1.f : 1.f;
                s = fmaf(sg * mpv[i], v[MSK[am ^ bm]], s);
            }
            wfl[row * 68 + kq * 8 + l2] = s;
        }
    }
    __syncthreads();

    // readout: thread group-of-8 owns one b-row; w row in registers;
    // ts reads: 8 distinct rows x 8-fold broadcast -> conflict-free.
    {
        const int rr = t >> 3, rl = t & 7;
        float4 wv[16];
#pragma unroll
        for (int cc = 0; cc < 16; ++cc)
            wv[cc] = *(const float4*)(wfl + rr * 68 + cc * 4);
#pragma unroll
        for (int k = 0; k < 12; ++k) {
            const int r = rl + (k << 3);
            if (r < R_) {
                float s = 0.f;
#pragma unroll
                for (int cc = 0; cc < 16; ++cc) {
                    const float4 tv = *(const float4*)(ts + r * 68 + cc * 4);
                    s += wv[cc].x * tv.x + wv[cc].y * tv.y
                       + wv[cc].z * tv.z + wv[cc].w * tv.w;
                }
                out[(size_t)(b0 + rr) * R_ + r] = 0.125f * s;
            }
        }
    }
}

extern "C" void kernel_launch(void* const* d_in, const int* in_sizes, int n_in,
                              void* d_out, int out_size, void* d_ws, size_t ws_size,
                              hipStream_t stream)
{
    const float* h_p = (const float*)d_in[0];
    const float* h_v = (const float*)d_in[1];
    const float* Wp1 = (const float*)d_in[2];
    const float* bp1 = (const float*)d_in[3];
    const float* lgp = (const float*)d_in[4];
    const float* lbp = (const float*)d_in[5];
    const float* Wp2 = (const float*)d_in[6];
    const float* bp2 = (const float*)d_in[7];
    const float* Wv1 = (const float*)d_in[8];
    const float* bv1 = (const float*)d_in[9];
    const float* lgv = (const float*)d_in[10];
    const float* lbv = (const float*)d_in[11];
    const float* Wv2 = (const float*)d_in[12];
    const float* bv2 = (const float*)d_in[13];
    const float* T   = (const float*)d_in[14];
    const float* gw  = (const float*)d_in[15];
    float* out = (float*)d_out;

    // ws layout (4.78 MB), R4/R7-verbatim:
    short* W1c_p = (short*)d_ws;                 // [16][256][32]
    short* W1c_v = W1c_p + 16 * 256 * 32;
    short* W2t_p = W1c_v + 16 * 256 * 32;        // [64][256]
    short* W2t_v = W2t_p + 64 * 256;
    short* mp    = W2t_v + 64 * 256;             // (B,64) bf16
    short* mv    = mp + (size_t)B_ * 64;         // (B,64) bf16

    cdd_prep_kernel<<<512, 256, 0, stream>>>(Wp1, Wv1, Wp2, Wv2,
                                             W1c_p, W1c_v, W2t_p, W2t_v);
    dim3 g1(B_ / 32, 2);
    cdd_proj_kernel<<<g1, 256, 0, stream>>>(h_p, h_v,
                                            bp1, lgp, lbp, bp2,
                                            bv1, lgv, lbv, bv2,
                                            W1c_p, W1c_v, W2t_p, W2t_v,
                                            mp, mv);
    cdd_cliff_kernel<<<B_ / 32, 256, 0, stream>>>(mp, mv, T, gw, out);
}

// Round 15
// 155.609 us; speedup vs baseline: 1.0174x; 1.0174x over previous
//
#include <hip/hip_runtime.h>
#include <math.h>

// CliffordDDIDecoder — R15 = R14 resubmitted verbatim (R14 never ran:
// GPUAcquisitionTimeout — no evidence gained). Delta vs R13 (passed,
// 158.3us; proj 42.9): upfront full-strip h register load. Diagnosis: h
// (67 MB) is HBM-cold each launch (the 268 MB ws poison-fill runs at 80%
// HBM peak and evicts L3); proj's invariant 42-52us across R7-R13 == 67 MB
// / ~1 TB/s. The rolling h prefetch never pipelined: each chunk consumes a
// W load (newest VMEM op) and s_waitcnt drains all OLDER ops — i.e. the h
// prefetch — every chunk. Fix: issue the thread's whole h share (16 float4,
// +64 VGPR, ~120 total) BEFORE any W load; the one-time drain then waits on
// a full-MLP burst (256 KB in flight per CU). Staging consumes the same
// regs in the same order — values bit-identical.
// cliff/prep R7-verbatim. MFMA readout stays BANNED (6/6 failure corr).

#define B_ 16384
#define D_ 512
#define H_ 256
#define R_ 95

typedef __attribute__((ext_vector_type(8))) short short8;   // 8 bf16
typedef __attribute__((ext_vector_type(4))) float f32x4;

#define MFMA(a, b, c) __builtin_amdgcn_mfma_f32_16x16x32_bf16(a, b, c, 0, 0, 0)

__device__ __forceinline__ short f2bf(float x) {            // fp32 -> bf16 RNE
    union { float f; unsigned u; } v; v.f = x;
    unsigned r = v.u + 0x7fffu + ((v.u >> 16) & 1u);
    return (short)(r >> 16);
}
__device__ __forceinline__ float bf2f(short s) {
    union { float f; unsigned u; } v;
    v.u = ((unsigned)(unsigned short)s) << 16;
    return v.f;
}

// exact GELU, erf via Abramowitz-Stegun 7.1.26 (max abs err 1.5e-7)
__device__ __forceinline__ float gelu_fast(float x) {
    const float z  = x * 0.70710678118654752f;
    const float az = fabsf(z);
    const float t  = 1.0f / fmaf(0.3275911f, az, 1.0f);
    float p = fmaf(1.061405429f, t, -1.453152027f);
    p = fmaf(p, t, 1.421413741f);
    p = fmaf(p, t, -0.284496736f);
    p = fmaf(p, t, 0.254829592f);
    p *= t;
    const float e  = 1.0f - p * __expf(-az * az);
    const float er = copysignf(e, z);
    return 0.5f * x * (1.0f + er);
}

// ---- prep: W1 -> [16 chunk][256 n][32 k] bf16 ; W2 -> [64 n][256 k] bf16 ----
__global__ __launch_bounds__(256)
void cdd_prep_kernel(const float* __restrict__ Wp1, const float* __restrict__ Wv1,
                     const float* __restrict__ Wp2, const float* __restrict__ Wv2,
                     short* __restrict__ W1c_p, short* __restrict__ W1c_v,
                     short* __restrict__ W2t_p, short* __restrict__ W2t_v)
{
    const int o = blockIdx.x * 256 + threadIdx.x;
    if (o < 16 * 256 * 32) {            // n-fast: coalesced W1 reads
        const int n = o & 255, kin = (o >> 8) & 31, ch = o >> 13;
        const int src = (ch * 32 + kin) * 256 + n;
        const int dst = ch * 8192 + n * 32 + kin;
        W1c_p[dst] = f2bf(Wp1[src]);
        W1c_v[dst] = f2bf(Wv1[src]);
    }
    if (o < 64 * 256) {
        const int n = o >> 8, k = o & 255;
        W2t_p[o] = f2bf(Wp2[k * 64 + n]);
        W2t_v[o] = f2bf(Wv2[k * 64 + n]);
    }
}

// ---- proj: x1=h@W1+b1 -> LN -> exact GELU -> m=x@W2+b2 (bf16 to ws) --------
// 32-row blocks, 256 thr (4 waves); wave w owns cols [64w,64w+64), mt 0..1.
// grid (512, 2) = 1024 blocks = 4 blocks/CU. LDS ~26 KB.
__global__ __launch_bounds__(256, 2)
void cdd_proj_kernel(const float* __restrict__ h_p, const float* __restrict__ h_v,
                     const float* __restrict__ bp1, const float* __restrict__ lgp,
                     const float* __restrict__ lbp, const float* __restrict__ bp2,
                     const float* __restrict__ bv1, const float* __restrict__ lgv,
                     const float* __restrict__ lbv, const float* __restrict__ bv2,
                     const short* __restrict__ W1c_p, const short* __restrict__ W1c_v,
                     const short* __restrict__ W2t_p, const short* __restrict__ W2t_v,
                     short* __restrict__ mp_out, short* __restrict__ mv_out)
{
    // hs: fragment-major quarter-strip (32 rows x 128 k), block bi = chl*2+mt:
    // 64 lanes x 8 bf16 contiguous -> ds_read_b128 lane-consecutive.
    __shared__ __align__(16) short hs[8 * 512];     // 8 KB
    __shared__ __align__(16) short xs[32 * 264];    // 16.9 KB
    __shared__ __align__(16) float lnbuf[256];      // 4 waves x 32 rows x 2

    const int which = blockIdx.y;
    const float* __restrict__ h   = which ? h_v : h_p;
    const float* __restrict__ b1  = which ? bv1 : bp1;
    const float* __restrict__ lg  = which ? lgv : lgp;
    const float* __restrict__ lb  = which ? lbv : lbp;
    const float* __restrict__ b2  = which ? bv2 : bp2;
    const short* __restrict__ W1c = which ? W1c_v : W1c_p;
    const short* __restrict__ W2t = which ? W2t_v : W2t_p;
    short* __restrict__ mo = which ? mv_out : mp_out;

    const int t = threadIdx.x;
    const int w = t >> 6, l = t & 63, q = l >> 4, c = l & 15;
    const int b0 = blockIdx.x * 32;
    // staging map: 8 threads/row; each thread covers 16 consecutive k of each
    // quarter (2 short8 writes). Per instr a wave covers 8 rows x 128 B.
    const int srow = t >> 3, kq8 = (t & 7) * 16;
    const int mt_s = srow >> 4, c_s = srow & 15;

    // ---- upfront full-strip h load: thread's whole 512-k share, issued
    // BEFORE any W load so the first vmcnt drain covers a full-MLP burst.
    const float* hbase = h + (size_t)(b0 + srow) * D_ + kq8;
    float4 ha[4][2], hb[4][2];
#pragma unroll
    for (int qh = 0; qh < 4; ++qh)
#pragma unroll
        for (int s = 0; s < 2; ++s) {
            ha[qh][s] = *(const float4*)(hbase + qh * 128 + s * 8);
            hb[qh][s] = *(const float4*)(hbase + qh * 128 + s * 8 + 4);
        }

    f32x4 acc1[2][4];
#pragma unroll
    for (int mt = 0; mt < 2; ++mt)
#pragma unroll
        for (int nt = 0; nt < 4; ++nt) acc1[mt][nt] = 0;

    const short* Wb0 = W1c + (w * 64 + c) * 32 + q * 8;
    short8 wb0[4], wb1[4];
#pragma unroll
    for (int nt = 0; nt < 4; ++nt) wb0[nt] = *(const short8*)(Wb0 + nt * 512);

#pragma unroll
    for (int qh = 0; qh < 4; ++qh) {
        // ---- stage this 128-k quarter (fragment-major bf16) from regs ----
        if (qh) __syncthreads();        // previous quarter's hs readers done
#pragma unroll
        for (int s = 0; s < 2; ++s) {
            short8 pk;
            pk[0] = f2bf(ha[qh][s].x); pk[1] = f2bf(ha[qh][s].y);
            pk[2] = f2bf(ha[qh][s].z); pk[3] = f2bf(ha[qh][s].w);
            pk[4] = f2bf(hb[qh][s].x); pk[5] = f2bf(hb[qh][s].y);
            pk[6] = f2bf(hb[qh][s].z); pk[7] = f2bf(hb[qh][s].w);
            // local k = kq8 + s*8 -> chunk chl = k>>5, quad qd = (k>>3)&3
            const int kk = kq8 + s * 8;
            const int chl = kk >> 5, qd = (kk >> 3) & 3;
            *(short8*)(hs + (chl * 2 + mt_s) * 512 + (qd * 16 + c_s) * 8) = pk;
        }
        __syncthreads();                // hs fully staged

        // ---- compute 4 chunks of this quarter; W register-dbuffered ----
#pragma unroll
        for (int chl = 0; chl < 4; ++chl) {
            const int g = qh * 4 + chl;                 // global chunk 0..15
            if (g < 15) {                               // prefetch next W batch
#pragma unroll
                for (int nt = 0; nt < 4; ++nt)
                    wb1[nt] = *(const short8*)(Wb0 + (g + 1) * 8192 + nt * 512);
            }
            const short8 a0 = *(const short8*)(hs + (chl * 2 + 0) * 512 + l * 8);
            const short8 a1 = *(const short8*)(hs + (chl * 2 + 1) * 512 + l * 8);
#pragma unroll
            for (int nt = 0; nt < 4; ++nt) {
                acc1[0][nt] = MFMA(a0, wb0[nt], acc1[0][nt]);
                acc1[1][nt] = MFMA(a1, wb0[nt], acc1[1][nt]);
            }
#pragma unroll
            for (int nt = 0; nt < 4; ++nt) wb0[nt] = wb1[nt];
        }
    }

    // ---------------- bias + LayerNorm (fp32 stats) + fast exact GELU ------
    float bb[4], gg[4], ee[4];
#pragma unroll
    for (int nt = 0; nt < 4; ++nt) {
        const int col = w * 64 + nt * 16 + c;
        bb[nt] = b1[col]; gg[nt] = lg[col]; ee[nt] = lb[col];
    }
#pragma unroll
    for (int mt = 0; mt < 2; ++mt)
#pragma unroll
        for (int reg = 0; reg < 4; ++reg) {
            float s1 = 0.f, s2 = 0.f;
#pragma unroll
            for (int nt = 0; nt < 4; ++nt) {
                const float a = acc1[mt][nt][reg] + bb[nt];
                acc1[mt][nt][reg] = a;
                s1 += a; s2 += a * a;
            }
#pragma unroll
            for (int m = 1; m <= 8; m <<= 1) {   // reduce over c (16 lanes)
                s1 += __shfl_xor(s1, m, 64);
                s2 += __shfl_xor(s2, m, 64);
            }
            if (c == 0) {
                const int row = mt * 16 + q * 4 + reg;
                *(float2*)(lnbuf + (w * 32 + row) * 2) = make_float2(s1, s2);
            }
        }
    __syncthreads();
#pragma unroll
    for (int mt = 0; mt < 2; ++mt)
#pragma unroll
        for (int reg = 0; reg < 4; ++reg) {
            const int row = mt * 16 + q * 4 + reg;
            float S1 = 0.f, S2 = 0.f;
#pragma unroll
            for (int w2 = 0; w2 < 4; ++w2) {
                const float2 p = *(const float2*)(lnbuf + (w2 * 32 + row) * 2);
                S1 += p.x; S2 += p.y;
            }
            const float mu  = S1 * (1.f / 256.f);
            const float var = S2 * (1.f / 256.f) - mu * mu;
            const float rs  = rsqrtf(var + 1e-5f);
#pragma unroll
            for (int nt = 0; nt < 4; ++nt) {
                const int col = w * 64 + nt * 16 + c;
                const float xv = (acc1[mt][nt][reg] - mu) * rs * gg[nt] + ee[nt];
                xs[row * 264 + col] = f2bf(gelu_fast(xv));
            }
        }
    __syncthreads();

    // ---------------- GEMM2: m(32x64) = xs(32x256) @ W2(256x64) + b2 -------
    // wave w owns n-cols [16w,16w+16); mt 0..1 (R7-proven pattern).
    f32x4 acc2[2]; acc2[0] = 0; acc2[1] = 0;
    const short* W2b = W2t + (w * 16 + c) * 256 + q * 8;
#pragma unroll
    for (int ks = 0; ks < 8; ++ks) {
        const short8 xa0 = *(const short8*)(xs + c * 264 + ks * 32 + q * 8);
        const short8 xa1 = *(const short8*)(xs + (16 + c) * 264 + ks * 32 + q * 8);
        const short8 wbk = *(const short8*)(W2b + ks * 32);
        acc2[0] = MFMA(xa0, wbk, acc2[0]);
        acc2[1] = MFMA(xa1, wbk, acc2[1]);
    }
    const float bc = b2[w * 16 + c];
#pragma unroll
    for (int mt = 0; mt < 2; ++mt)
#pragma unroll
        for (int reg = 0; reg < 4; ++reg) {
            const int row = mt * 16 + q * 4 + reg;
            mo[(size_t)(b0 + row) * 64 + w * 16 + c] = f2bf(acc2[mt][reg] + bc);
        }
}

// ---- cliff: R7-verbatim — Clifford collapse + VALU-dot readout, T in LDS ---
__global__ __launch_bounds__(256, 2)
void cdd_cliff_kernel(const short* __restrict__ mp, const short* __restrict__ mv,
                      const float* __restrict__ T, const float* __restrict__ gw,
                      float* __restrict__ out)
{
    __shared__ __align__(16) float wfl[32 * 68];    // collapsed w, fp32
    __shared__ __align__(16) float ts[95 * 68];     // T staged (pad 68)
    const int t  = threadIdx.x;
    const int b0 = blockIdx.x * 32;

    // stage T: 95 rows x 16 float4
#pragma unroll
    for (int k = 0; k < 6; ++k) {
        const int o = t + k * 256;
        if (o < 95 * 16) {
            const int rr = o >> 4, c4 = (o & 15) << 2;
            *(float4*)(ts + rr * 68 + c4) = *(const float4*)(T + rr * 64 + c4);
        }
    }

    // collapse: w[row][kq*8 .. +8] from mp,mv (fp32 math, bf16 inputs)
    {
        const int row = t >> 3, kq = t & 7;
        float g[8];
#pragma unroll
        for (int i = 0; i < 8; ++i) g[i] = gw[i];
        const short8 p8 = *(const short8*)(mp + (size_t)(b0 + row) * 64 + kq * 8);
        const short8 q8 = *(const short8*)(mv + (size_t)(b0 + row) * 64 + kq * 8);
        float mpv[8], mvv[8];
#pragma unroll
        for (int i = 0; i < 8; ++i) { mpv[i] = bf2f(p8[i]); mvv[i] = bf2f(q8[i]); }

        constexpr int MSK[8] = {0, 1, 2, 4, 3, 5, 6, 7};
        float v[8];
#pragma unroll
        for (int m = 0; m < 8; ++m) {
            float s = 0.f;
#pragma unroll
            for (int j = 0; j < 8; ++j) {
                const int am = MSK[m], bm = MSK[j];
                const int par = (__popc((am >> 1) & bm) + __popc((am >> 2) & bm)) & 1;
                const float sg = par ? -1.f : 1.f;
                s = fmaf(sg * g[MSK[am ^ bm]], mvv[j], s);
            }
            v[m] = s;
        }
#pragma unroll
        for (int l2 = 0; l2 < 8; ++l2) {
            float s = 0.f;
#pragma unroll
            for (int i = 0; i < 8; ++i) {
                const int am = MSK[i], bm = MSK[l2];
                const int par = (__popc((am >> 1) & bm) + __popc((am >> 2) & bm)) & 1;
                const float sg = par ? -1.f : 1.f;
                s = fmaf(sg * mpv[i], v[MSK[am ^ bm]], s);
            }
            wfl[row * 68 + kq * 8 + l2] = s;
        }
    }
    __syncthreads();

    // readout: thread group-of-8 owns one b-row; w row in registers;
    // ts reads: 8 distinct rows x 8-fold broadcast -> conflict-free.
    {
        const int rr = t >> 3, rl = t & 7;
        float4 wv[16];
#pragma unroll
        for (int cc = 0; cc < 16; ++cc)
            wv[cc] = *(const float4*)(wfl + rr * 68 + cc * 4);
#pragma unroll
        for (int k = 0; k < 12; ++k) {
            const int r = rl + (k << 3);
            if (r < R_) {
                float s = 0.f;
#pragma unroll
                for (int cc = 0; cc < 16; ++cc) {
                    const float4 tv = *(const float4*)(ts + r * 68 + cc * 4);
                    s += wv[cc].x * tv.x + wv[cc].y * tv.y
                       + wv[cc].z * tv.z + wv[cc].w * tv.w;
                }
                out[(size_t)(b0 + rr) * R_ + r] = 0.125f * s;
            }
        }
    }
}

extern "C" void kernel_launch(void* const* d_in, const int* in_sizes, int n_in,
                              void* d_out, int out_size, void* d_ws, size_t ws_size,
                              hipStream_t stream)
{
    const float* h_p = (const float*)d_in[0];
    const float* h_v = (const float*)d_in[1];
    const float* Wp1 = (const float*)d_in[2];
    const float* bp1 = (const float*)d_in[3];
    const float* lgp = (const float*)d_in[4];
    const float* lbp = (const float*)d_in[5];
    const float* Wp2 = (const float*)d_in[6];
    const float* bp2 = (const float*)d_in[7];
    const float* Wv1 = (const float*)d_in[8];
    const float* bv1 = (const float*)d_in[9];
    const float* lgv = (const float*)d_in[10];
    const float* lbv = (const float*)d_in[11];
    const float* Wv2 = (const float*)d_in[12];
    const float* bv2 = (const float*)d_in[13];
    const float* T   = (const float*)d_in[14];
    const float* gw  = (const float*)d_in[15];
    float* out = (float*)d_out;

    // ws layout (4.78 MB), R4/R7-verbatim:
    short* W1c_p = (short*)d_ws;                 // [16][256][32]
    short* W1c_v = W1c_p + 16 * 256 * 32;
    short* W2t_p = W1c_v + 16 * 256 * 32;        // [64][256]
    short* W2t_v = W2t_p + 64 * 256;
    short* mp    = W2t_v + 64 * 256;             // (B,64) bf16
    short* mv    = mp + (size_t)B_ * 64;         // (B,64) bf16

    cdd_prep_kernel<<<512, 256, 0, stream>>>(Wp1, Wv1, Wp2, Wv2,
                                             W1c_p, W1c_v, W2t_p, W2t_v);
    dim3 g1(B_ / 32, 2);
    cdd_proj_kernel<<<g1, 256, 0, stream>>>(h_p, h_v,
                                            bp1, lgp, lbp, bp2,
                                            bv1, lgv, lbv, bv2,
                                            W1c_p, W1c_v, W2t_p, W2t_v,
                                            mp, mv);
    cdd_cliff_kernel<<<B_ / 32, 256, 0, stream>>>(mp, mv, T, gw, out);
}